// Round 1
// baseline (417.841 us; speedup 1.0000x reference)
//
#include <hip/hip_runtime.h>
#include <cstdint>
#include <cstddef>

// Problem constants (fixed shapes from setup_inputs)
#define IN_DIM  1024
#define OUT_DIM 1024
#define NB      7
#define KTOT    8192   // 1024 (linear) + 1024*7 (spline basis)
#define BROWS   8192   // batch

typedef unsigned short u16;
typedef __attribute__((ext_vector_type(8))) short bf16x8;   // 8 bf16 = 4 VGPRs (guide §3)
typedef __attribute__((ext_vector_type(4))) float f32x4;
typedef __attribute__((ext_vector_type(4))) unsigned short u16x4;

__device__ __forceinline__ u16 f2bf(float f) {
    union { float f; unsigned int u; } v; v.f = f;
    unsigned int r = (v.u + 0x7fffu + ((v.u >> 16) & 1u)) >> 16;  // RTN-even
    return (u16)r;
}

__device__ __forceinline__ void gl_lds16(const u16* g, u16* l) {
    __builtin_amdgcn_global_load_lds(
        (const __attribute__((address_space(1))) void*)g,
        (__attribute__((address_space(3))) void*)l,
        16, 0, 0);
}

// ---------------------------------------------------------------------------
// prep_w: Bt[o][i] = bf16(W[o][i]) for i<1024. Fully coalesced both sides.
// grid 1024 x 256 threads, 4 floats/thread.
__global__ __launch_bounds__(256) void prep_w(const float* __restrict__ W,
                                              u16* __restrict__ Bt) {
    int idx = blockIdx.x * 256 + threadIdx.x;   // 0..262143
    int o  = idx >> 8;                          // 256 float4-chunks per row
    int i4 = (idx & 255) * 4;
    float4 v = *(const float4*)&W[(size_t)o * IN_DIM + i4];
    u16x4 u = { f2bf(v.x), f2bf(v.y), f2bf(v.z), f2bf(v.w) };
    *(u16x4*)&Bt[(size_t)o * KTOT + i4] = u;
}

// ---------------------------------------------------------------------------
// prep_sw: Bt[o][1024 + i*7 + k] = bf16(sw[i][o][k]).  LDS transpose:
// block = (i-tile of 4) x (o-half of 512). Reads contiguous per i-row,
// writes contiguous 28-elem runs per o-row.
__global__ __launch_bounds__(256) void prep_sw(const float* __restrict__ sw,
                                               u16* __restrict__ Bt) {
    __shared__ u16 S[4 * 3584];                 // [i_local][o_local*7 + k], 28 KB
    const int i0 = blockIdx.x * 4;
    const int o0 = blockIdx.y * 512;
    const int t  = threadIdx.x;
    #pragma unroll
    for (int r = 0; r < 4; ++r) {
        const float* src = sw + (size_t)(i0 + r) * (IN_DIM * NB) / 1 * 0 /*dummy*/ +
                           (size_t)(i0 + r) * (OUT_DIM * NB) + (size_t)o0 * NB;
        for (int c = t; c < 3584; c += 256)
            S[r * 3584 + c] = f2bf(src[c]);
    }
    __syncthreads();
    for (int f = t; f < 14336; f += 256) {      // 512 o-rows * 28 elems
        int o = f / 28;
        int r = f - o * 28;                      // r = i_local*7 + k
        int i = r / 7;
        int k = r - i * 7;
        Bt[(size_t)(o0 + o) * KTOT + IN_DIM + (size_t)i0 * NB + r] =
            S[i * 3584 + o * NB + k];
    }
}

// ---------------------------------------------------------------------------
// prep_a: A[b][0..1023] = bf16(x[b][i]); A[b][1024+i*7+k] = bf16(basis_k(tanh(x))).
// Faithful replication of the reference Cox-de Boor recursion (indices 0..6 only,
// zero-padded shift => basis == 0 for t >= 0.4 exactly as the reference computes).
__global__ __launch_bounds__(256) void prep_a(const float* __restrict__ x,
                                              u16* __restrict__ A, int row0) {
    int gid = blockIdx.x * 256 + threadIdx.x;
    int b = gid >> 10;          // local row within chunk
    int i = gid & 1023;
    float xv = x[(size_t)(row0 + b) * IN_DIM + i];
    size_t base = (size_t)b * KTOT;
    A[base + i] = f2bf(xv);

    float t = tanhf(xv);
    t = fminf(fmaxf(t, -1.f), 1.f);

    const float kn[11] = {-1.f, -0.8f, -0.6f, -0.4f, -0.2f, 0.f,
                           0.2f, 0.4f, 0.6f, 0.8f, 1.f};
    float bb[8];
    #pragma unroll
    for (int j = 0; j < 7; ++j)
        bb[j] = (t >= kn[j] && t < kn[j + 1]) ? 1.f : 0.f;
    bb[7] = 0.f;

    const float rcp[4] = {0.f, 5.f, 2.5f, 5.f / 3.f};  // 1/(0.2*d)
    #pragma unroll
    for (int d = 1; d <= 3; ++d) {
        #pragma unroll
        for (int j = 0; j < 7; ++j) {
            float left  = (t - kn[j]) * rcp[d];
            float right = (kn[j + d + 1] - t) * rcp[d];
            bb[j] = left * bb[j] + right * bb[j + 1];  // ascending: bb[j+1] still old
        }
    }
    size_t base2 = base + IN_DIM + (size_t)i * NB;
    #pragma unroll
    for (int k = 0; k < NB; ++k) A[base2 + k] = f2bf(bb[k]);
}

// ---------------------------------------------------------------------------
// gemm_bt: C[m][n] = sum_k A[m][k]*Bt[n][k] + bias[n].  m97-ladder structure:
// 128x128 tile, BK=32, 4 waves each computing 64x64 via 4x4 of 16x16x32 MFMA,
// global_load_lds width=16 staging, bf16 in / fp32 accumulate.
__global__ __launch_bounds__(256) void gemm_bt(const u16* __restrict__ A,
                                               const u16* __restrict__ Bt,
                                               const float* __restrict__ bias,
                                               float* __restrict__ C) {
    __shared__ __align__(16) u16 As[128 * 32];   // 8 KB
    __shared__ __align__(16) u16 Bs[128 * 32];   // 8 KB
    const int t = threadIdx.x;
    const int L = t & 63;
    const int w = t >> 6;
    const int wm = w & 1, wn = w >> 1;
    const int m0 = blockIdx.y * 128;
    const int n0 = blockIdx.x * 128;

    f32x4 acc[4][4] = {};

    // staging: thread t stages rows t>>2 and 64+(t>>2), k-chunk (t&3)*8.
    // LDS dest = wave-uniform base + lane*16B (global_load_lds constraint).
    const int srow = t >> 2;
    const int sch  = (t & 3) * 8;
    const u16* gA0 = A  + (size_t)(m0 + srow) * KTOT + sch;
    const u16* gA1 = gA0 + (size_t)64 * KTOT;
    const u16* gB0 = Bt + (size_t)(n0 + srow) * KTOT + sch;
    const u16* gB1 = gB0 + (size_t)64 * KTOT;
    u16* lA0 = &As[t * 8];  u16* lA1 = &As[2048 + t * 8];
    u16* lB0 = &Bs[t * 8];  u16* lB1 = &Bs[2048 + t * 8];

    const int lm = L & 15;
    const int kq = (L >> 4) * 8;   // A-frag: A[m=lane&15][k=(lane>>4)*8 + j]

    for (int ko = 0; ko < KTOT; ko += 32) {
        __syncthreads();
        gl_lds16(gA0 + ko, lA0);
        gl_lds16(gA1 + ko, lA1);
        gl_lds16(gB0 + ko, lB0);
        gl_lds16(gB1 + ko, lB1);
        __syncthreads();   // compiler emits vmcnt(0) drain before s_barrier

        bf16x8 af[4], bfr[4];
        #pragma unroll
        for (int mi = 0; mi < 4; ++mi)
            af[mi] = *(const bf16x8*)&As[(wm * 64 + mi * 16 + lm) * 32 + kq];
        #pragma unroll
        for (int ni = 0; ni < 4; ++ni)
            bfr[ni] = *(const bf16x8*)&Bs[(wn * 64 + ni * 16 + lm) * 32 + kq];
        #pragma unroll
        for (int mi = 0; mi < 4; ++mi)
            #pragma unroll
            for (int ni = 0; ni < 4; ++ni)
                acc[mi][ni] = __builtin_amdgcn_mfma_f32_16x16x32_bf16(
                    af[mi], bfr[ni], acc[mi][ni], 0, 0, 0);
    }

    // epilogue: C/D layout col=lane&15, row=(lane>>4)*4+reg (m89-verified)
    const int r0 = (L >> 4) * 4;
    #pragma unroll
    for (int ni = 0; ni < 4; ++ni) {
        int col = n0 + wn * 64 + ni * 16 + lm;
        float bv = bias[col];
        #pragma unroll
        for (int mi = 0; mi < 4; ++mi) {
            int rb = m0 + wm * 64 + mi * 16 + r0;
            f32x4 v = acc[mi][ni];
            #pragma unroll
            for (int r = 0; r < 4; ++r)
                C[(size_t)(rb + r) * OUT_DIM + col] = v[r] + bv;
        }
    }
}

// ---------------------------------------------------------------------------
extern "C" void kernel_launch(void* const* d_in, const int* in_sizes, int n_in,
                              void* d_out, int out_size, void* d_ws, size_t ws_size,
                              hipStream_t stream) {
    (void)in_sizes; (void)n_in; (void)out_size;
    const float* x    = (const float*)d_in[0];
    const float* sw   = (const float*)d_in[1];
    const float* W    = (const float*)d_in[2];
    const float* bias = (const float*)d_in[3];
    // d_in[4] = knots: fixed linspace(-1,1,11) -> compile-time constants
    float* out = (float*)d_out;

    const size_t btBytes = (size_t)OUT_DIM * KTOT * 2;     // 16 MB
    u16* Bt = (u16*)d_ws;
    u16* A  = (u16*)((char*)d_ws + btBytes);

    prep_w<<<1024, 256, 0, stream>>>(W, Bt);
    prep_sw<<<dim3(IN_DIM / 4, 2), 256, 0, stream>>>(sw, Bt);

    // chunk batch if workspace is too small for the full 128 MB A matrix
    int nchunks = 1;
    if (ws_size < btBytes + (size_t)BROWS * KTOT * 2)       nchunks = 2;
    if (ws_size < btBytes + (size_t)(BROWS / 2) * KTOT * 2) nchunks = 4;
    if (ws_size < btBytes + (size_t)(BROWS / 4) * KTOT * 2) nchunks = 8;
    const int rows = BROWS / nchunks;

    for (int c = 0; c < nchunks; ++c) {
        int row0 = c * rows;
        prep_a<<<rows * 4, 256, 0, stream>>>(x, A, row0);
        gemm_bt<<<dim3(OUT_DIM / 128, rows / 128), 256, 0, stream>>>(
            A, Bt, bias, out + (size_t)row0 * OUT_DIM);
    }
}

// Round 2
// 323.810 us; speedup vs baseline: 1.2904x; 1.2904x over previous
//
#include <hip/hip_runtime.h>
#include <cstdint>
#include <cstddef>

// Problem constants (fixed shapes from setup_inputs)
#define IN_DIM  1024
#define OUT_DIM 1024
#define NB      7
#define KTOT    8192   // interleaved: k = i*8 + {x, basis0..basis6}
#define BROWS   8192   // batch

typedef unsigned short u16;
typedef __attribute__((ext_vector_type(8))) short bf16x8;
typedef __attribute__((ext_vector_type(8))) unsigned short u16x8;
typedef __attribute__((ext_vector_type(4))) float f32x4;

__device__ __forceinline__ u16 f2bf(float f) {
    union { float f; unsigned int u; } v; v.f = f;
    unsigned int r = (v.u + 0x7fffu + ((v.u >> 16) & 1u)) >> 16;  // RTN-even
    return (u16)r;
}

__device__ __forceinline__ void gl_lds16(const u16* g, u16* l) {
    __builtin_amdgcn_global_load_lds(
        (const __attribute__((address_space(1))) void*)g,
        (__attribute__((address_space(3))) void*)l,
        16, 0, 0);
}

// ---------------------------------------------------------------------------
// prep_wsw: Bt[o][i*8+0] = bf16(W[o][i]); Bt[o][i*8+1+k] = bf16(sw[i][o][k]).
// Tile: 8 i x 256 o. sw reads are contiguous runs of 1792 floats per i-row;
// writes are aligned 16B u16x8 chunks, coalesced over consecutive threads.
__global__ __launch_bounds__(256) void prep_wsw(const float* __restrict__ sw,
                                                const float* __restrict__ W,
                                                u16* __restrict__ Bt) {
    __shared__ u16 S[8 * 256 * 8];               // [il][ol][slot], 32 KB
    const int i0 = blockIdx.x * 8;
    const int o0 = blockIdx.y * 256;
    const int t  = threadIdx.x;
    #pragma unroll
    for (int il = 0; il < 8; ++il) {
        const float* src = sw + ((size_t)(i0 + il) * OUT_DIM + o0) * NB;
        for (int c = t; c < 256 * NB; c += 256) {
            int ol = c / 7, k = c - ol * 7;
            S[(il * 256 + ol) * 8 + 1 + k] = f2bf(src[c]);
        }
    }
    for (int c = t; c < 2048; c += 256) {
        int ol = c >> 3, il = c & 7;
        S[(il * 256 + ol) * 8] = f2bf(W[(size_t)(o0 + ol) * IN_DIM + i0 + il]);
    }
    __syncthreads();
    for (int c = t; c < 2048; c += 256) {
        int ol = c >> 3, il = c & 7;   // consecutive t -> consecutive il -> contiguous 16B
        *(u16x8*)&Bt[(size_t)(o0 + ol) * KTOT + (size_t)(i0 + il) * 8] =
            *(const u16x8*)&S[(il * 256 + ol) * 8];
    }
}

// ---------------------------------------------------------------------------
// prep_a: A[b][i*8+0] = bf16(x[b][i]); A[b][i*8+1+k] = bf16(basis_k(tanh(x))).
// One aligned 16B store per thread, fully coalesced. Basis recursion is a
// faithful replication of the reference (7-wide, zero-padded shift).
__global__ __launch_bounds__(256) void prep_a(const float* __restrict__ x,
                                              u16* __restrict__ A, int row0) {
    int gid = blockIdx.x * 256 + threadIdx.x;
    int b = gid >> 10;          // local row within chunk
    int i = gid & 1023;
    float xv = x[(size_t)(row0 + b) * IN_DIM + i];

    float t = tanhf(xv);
    t = fminf(fmaxf(t, -1.f), 1.f);

    const float kn[11] = {-1.f, -0.8f, -0.6f, -0.4f, -0.2f, 0.f,
                           0.2f, 0.4f, 0.6f, 0.8f, 1.f};
    float bb[8];
    #pragma unroll
    for (int j = 0; j < 7; ++j)
        bb[j] = (t >= kn[j] && t < kn[j + 1]) ? 1.f : 0.f;
    bb[7] = 0.f;

    const float rcp[4] = {0.f, 5.f, 2.5f, 5.f / 3.f};  // 1/(0.2*d)
    #pragma unroll
    for (int d = 1; d <= 3; ++d) {
        #pragma unroll
        for (int j = 0; j < 7; ++j) {
            float left  = (t - kn[j]) * rcp[d];
            float right = (kn[j + d + 1] - t) * rcp[d];
            bb[j] = left * bb[j] + right * bb[j + 1];  // ascending: bb[j+1] still old
        }
    }
    u16x8 outv;
    outv[0] = f2bf(xv);
    #pragma unroll
    for (int k = 0; k < NB; ++k) outv[1 + k] = f2bf(bb[k]);
    *(u16x8*)&A[(size_t)b * KTOT + (size_t)i * 8] = outv;
}

// ---------------------------------------------------------------------------
// gemm_bt: C[m][n] = sum_k A[m][k]*Bt[n][k] + bias[n].  m97 structure:
// 128x128 tile, BK=32, 4 waves x (4x4 of 16x16x32 MFMA), global_load_lds
// width=16 staging. 1-D grid with XCD swizzle: all 8 n-tiles of one m-tile
// share L%8 (same XCD under round-robin dispatch) -> A-tile shared in L2.
__global__ __launch_bounds__(256) void gemm_bt(const u16* __restrict__ A,
                                               const u16* __restrict__ Bt,
                                               const float* __restrict__ bias,
                                               float* __restrict__ C) {
    __shared__ __align__(16) u16 As[128 * 32];   // 8 KB
    __shared__ __align__(16) u16 Bs[128 * 32];   // 8 KB
    const int t = threadIdx.x;
    const int L = t & 63;
    const int w = t >> 6;
    const int wm = w & 1, wn = w >> 1;

    // XCD swizzle: r = XCD slot, q>>3 selects m-group, q&7 the n-tile
    const int Lid = blockIdx.x;
    const int r   = Lid & 7;
    const int q   = Lid >> 3;
    const int n_t = q & 7;
    const int m_t = r + 8 * (q >> 3);
    const int m0 = m_t * 128;
    const int n0 = n_t * 128;

    f32x4 acc[4][4] = {};

    const int srow = t >> 2;
    const int sch  = (t & 3) * 8;
    const u16* gA0 = A  + (size_t)(m0 + srow) * KTOT + sch;
    const u16* gA1 = gA0 + (size_t)64 * KTOT;
    const u16* gB0 = Bt + (size_t)(n0 + srow) * KTOT + sch;
    const u16* gB1 = gB0 + (size_t)64 * KTOT;
    u16* lA0 = &As[t * 8];  u16* lA1 = &As[2048 + t * 8];
    u16* lB0 = &Bs[t * 8];  u16* lB1 = &Bs[2048 + t * 8];

    const int lm = L & 15;
    const int kq = (L >> 4) * 8;   // A-frag: A[m=lane&15][k=(lane>>4)*8 + j]

    for (int ko = 0; ko < KTOT; ko += 32) {
        __syncthreads();
        gl_lds16(gA0 + ko, lA0);
        gl_lds16(gA1 + ko, lA1);
        gl_lds16(gB0 + ko, lB0);
        gl_lds16(gB1 + ko, lB1);
        __syncthreads();

        bf16x8 af[4], bfr[4];
        #pragma unroll
        for (int mi = 0; mi < 4; ++mi)
            af[mi] = *(const bf16x8*)&As[(wm * 64 + mi * 16 + lm) * 32 + kq];
        #pragma unroll
        for (int ni = 0; ni < 4; ++ni)
            bfr[ni] = *(const bf16x8*)&Bs[(wn * 64 + ni * 16 + lm) * 32 + kq];
        #pragma unroll
        for (int mi = 0; mi < 4; ++mi)
            #pragma unroll
            for (int ni = 0; ni < 4; ++ni)
                acc[mi][ni] = __builtin_amdgcn_mfma_f32_16x16x32_bf16(
                    af[mi], bfr[ni], acc[mi][ni], 0, 0, 0);
    }

    // epilogue: C/D layout col=lane&15, row=(lane>>4)*4+reg (m89-verified)
    const int r0 = (L >> 4) * 4;
    #pragma unroll
    for (int ni = 0; ni < 4; ++ni) {
        int col = n0 + wn * 64 + ni * 16 + lm;
        float bv = bias[col];
        #pragma unroll
        for (int mi = 0; mi < 4; ++mi) {
            int rb = m0 + wm * 64 + mi * 16 + r0;
            f32x4 v = acc[mi][ni];
            #pragma unroll
            for (int rr = 0; rr < 4; ++rr)
                C[(size_t)(rb + rr) * OUT_DIM + col] = v[rr] + bv;
        }
    }
}

// ---------------------------------------------------------------------------
extern "C" void kernel_launch(void* const* d_in, const int* in_sizes, int n_in,
                              void* d_out, int out_size, void* d_ws, size_t ws_size,
                              hipStream_t stream) {
    (void)in_sizes; (void)n_in; (void)out_size;
    const float* x    = (const float*)d_in[0];
    const float* sw   = (const float*)d_in[1];
    const float* W    = (const float*)d_in[2];
    const float* bias = (const float*)d_in[3];
    // d_in[4] = knots: fixed linspace(-1,1,11) -> compile-time constants
    float* out = (float*)d_out;

    const size_t btBytes = (size_t)OUT_DIM * KTOT * 2;     // 16 MB
    u16* Bt = (u16*)d_ws;
    u16* A  = (u16*)((char*)d_ws + btBytes);

    prep_wsw<<<dim3(IN_DIM / 8, OUT_DIM / 256), 256, 0, stream>>>(sw, W, Bt);

    // chunk batch if workspace is too small for the full 128 MB A matrix
    int nchunks = 1;
    if (ws_size < btBytes + (size_t)BROWS * KTOT * 2)       nchunks = 2;
    if (ws_size < btBytes + (size_t)(BROWS / 2) * KTOT * 2) nchunks = 4;
    if (ws_size < btBytes + (size_t)(BROWS / 4) * KTOT * 2) nchunks = 8;
    const int rows = BROWS / nchunks;

    for (int c = 0; c < nchunks; ++c) {
        int row0 = c * rows;
        prep_a<<<rows * 4, 256, 0, stream>>>(x, A, row0);
        gemm_bt<<<dim3(8 * (rows / 128)), 256, 0, stream>>>(
            A, Bt, bias, out + (size_t)row0 * OUT_DIM);
    }
}